// Round 14
// baseline (244.993 us; speedup 1.0000x reference)
//
#include <hip/hip_runtime.h>
#include <hip/hip_bf16.h>

typedef __attribute__((ext_vector_type(2))) float f2v;
typedef __attribute__((ext_vector_type(4))) float f4v;
typedef __attribute__((ext_vector_type(8))) short bf8v;
typedef __attribute__((ext_vector_type(8))) _Float16 h8v;

// ---- problem constants ----
#define NPOS 32768            // 32*32*32
#define CCH  192
#define HID  768

// ---- workspace layout (bytes) ----
#define WS_Y    ((size_t)0)           // 25,165,824  conv out bf16, cell layout
#define WS_B1F  ((size_t)25165824)    // 294,912  w1 bf16 B-frag swizzled
#define WS_B2F  ((size_t)25460736)    // 294,912  w2 bf16 B-frag swizzled
#define WS_WPF  ((size_t)25755648)    // 301,056  dot2 pairs (tier2) / cell list (tier1)
#define WS_B3F  ((size_t)26056704)    // 9,633,792  conv Toeplitz B-frags f16 (192*49 x 1KB)
#define WS_TOTAL_MFMA ((size_t)35690496)
#define WS_TOTAL_DOT2 ((size_t)26056704)

__device__ inline unsigned short f2bf(float f){
  unsigned int u = __float_as_uint(f);
  u += 0x7FFFu + ((u >> 16) & 1u);      // RNE
  return (unsigned short)(u >> 16);
}
__device__ inline float bf2f(unsigned short s){
  return __uint_as_float(((unsigned int)s) << 16);
}
__device__ inline float gelu_f(float x){
  float u = 0.7978845608028654f * x * fmaf(0.044715f, x*x, 1.0f);
  float e = __expf(2.0f*u);
  float th = __fdividef(e - 1.0f, e + 1.0f);
  return 0.5f*x*(1.0f + th);
}

#define DOT2(A, X, W) \
  asm("v_dot2_f32_f16 %0, %1, %2, %0" : "+v"(A) : "v"(X), "s"(W))

// ---------------------------------------------------------------------------
// Kernel 0: mask compaction (1 block). Ordered list: active [0..na), then
// inactive; list[1024] = na.
// ---------------------------------------------------------------------------
__global__ __launch_bounds__(256) void compact_kernel(
    const int* __restrict__ mask, int* __restrict__ list)
{
  __shared__ unsigned short cnt[256];
  __shared__ int pref[257];
  int t = threadIdx.x;
  int m[4], c0 = 0;
  #pragma unroll
  for (int i = 0; i < 4; ++i) { m[i] = mask[t*4 + i]; c0 += (m[i] != 0); }
  cnt[t] = (unsigned short)c0;
  __syncthreads();
  if (t == 0) {
    int s = 0;
    for (int i = 0; i < 256; ++i) { pref[i] = s; s += cnt[i]; }
    pref[256] = s;
  }
  __syncthreads();
  int na = pref[256];
  int pa = pref[t];
  int pi = na + (t*4 - pref[t]);
  #pragma unroll
  for (int i = 0; i < 4; ++i) {
    if (m[i]) list[pa++] = t*4 + i;
    else      list[pi++] = t*4 + i;
  }
  if (t == 0) list[1024] = na;
}

// ---------------------------------------------------------------------------
// Kernel 1 (main): depthwise 7x7x7 conv + bias as implicit GEMM on MFMA (f16).
// (Geometry verified r7; kz-grouped B loads r8. Unchanged this round.)
// ---------------------------------------------------------------------------
#define ZSTR 712
__global__ __launch_bounds__(256) void conv_mfma_kernel(
    const float* __restrict__ x, const float* __restrict__ dw_b,
    const unsigned short* __restrict__ b3f, unsigned short* __restrict__ yc)
{
  __shared__ unsigned short tile[22*ZSTR];    // 31,328 B

  int bid = blockIdx.x;                // 3072 = 192c * 16(r)
  int c = bid % 192;
  int r = bid / 192;                   // 0..15
  int xq = r & 1, yq = (r >> 1) & 1, zh = (r >> 2) & 1, b = r >> 3;
  int tx0 = xq*16, ty0 = yq*16, zb = zh*16;

  int tid = threadIdx.x;
  const float* xsrc = x + ((size_t)(b*CCH + c))*NPOS;

  #pragma unroll
  for (int it = 0; it < 8; ++it) {
    int idx = tid + 256*it;            // 0..1935
    if (idx < 1936) {
      int ci = idx & 3;
      int row = idx >> 2;
      int lz = row / 22, ly = row - lz*22;
      int gz = zb - 3 + lz, gy = ty0 - 3 + ly;
      f4v v0 = {0.f,0.f,0.f,0.f}, v1 = {0.f,0.f,0.f,0.f};
      if (((unsigned)gz < 32u) & ((unsigned)gy < 32u) & (ci < 3)) {
        int gx0 = tx0 - 4 + 8*ci;
        const float* src = xsrc + (size_t)gz*1024 + gy*32;
        if ((unsigned)gx0 <= 28u)     v0 = *(const f4v*)(src + gx0);
        if ((unsigned)(gx0+4) <= 28u) v1 = *(const f4v*)(src + gx0 + 4);
      }
      h8v pk;
      pk[0] = (_Float16)v0[0]; pk[1] = (_Float16)v0[1];
      pk[2] = (_Float16)v0[2]; pk[3] = (_Float16)v0[3];
      pk[4] = (_Float16)v1[0]; pk[5] = (_Float16)v1[1];
      pk[6] = (_Float16)v1[2]; pk[7] = (_Float16)v1[3];
      *(h8v*)(tile + lz*ZSTR + ly*32 + ci*8) = pk;
    }
  }
  __syncthreads();

  int wv = tid >> 6, lane = tid & 63;
  int q = lane >> 4, zm = lane & 15;

  const unsigned short* abase = tile + (size_t)zm*ZSTR + q*8;
  const unsigned short* bbase = b3f + ((size_t)c*49)*512 + (size_t)lane*8;

  f4v acc[4];
  #pragma unroll
  for (int t = 0; t < 4; ++t) acc[t] = (f4v){0.f,0.f,0.f,0.f};

  #pragma unroll 1
  for (int kz = 0; kz < 7; ++kz) {
    h8v Bt[7];
    #pragma unroll
    for (int ky = 0; ky < 7; ++ky)
      Bt[ky] = *(const h8v*)(bbase + (size_t)(kz*7 + ky)*512);
    h8v Af[10];
    #pragma unroll
    for (int rr = 0; rr < 10; ++rr)
      Af[rr] = *(const h8v*)(abase + kz*ZSTR + (4*wv + rr)*32);
    #pragma unroll
    for (int ky = 0; ky < 7; ++ky) {
      acc[0] = __builtin_amdgcn_mfma_f32_16x16x32_f16(Af[ky+0], Bt[ky], acc[0], 0, 0, 0);
      acc[1] = __builtin_amdgcn_mfma_f32_16x16x32_f16(Af[ky+1], Bt[ky], acc[1], 0, 0, 0);
      acc[2] = __builtin_amdgcn_mfma_f32_16x16x32_f16(Af[ky+2], Bt[ky], acc[2], 0, 0, 0);
      acc[3] = __builtin_amdgcn_mfma_f32_16x16x32_f16(Af[ky+3], Bt[ky], acc[3], 0, 0, 0);
    }
  }

  float bias = dw_b[c];
  int cz = zh*4 + q;
  int cx = (tx0 >> 2) + (zm >> 2);
  int xr = zm & 3;
  int cy = (ty0 >> 2) + wv;
  int cell = cz*64 + cy*8 + cx;
  unsigned short* yb0 = yc + (((size_t)(b*512 + cell))*192 + c)*64 + xr;
  #pragma unroll
  for (int t = 0; t < 4; ++t) {
    unsigned short* yb = yb0 + t*4;
    yb[0]  = f2bf(acc[t][0] + bias);
    yb[16] = f2bf(acc[t][1] + bias);
    yb[32] = f2bf(acc[t][2] + bias);
    yb[48] = f2bf(acc[t][3] + bias);
  }
}

// ---------------------------------------------------------------------------
// Kernel 1 (tier-2 fallback): dot2 f16 path.
// ---------------------------------------------------------------------------
__global__ __launch_bounds__(256, 6) void conv_dw_f16_kernel(
    const float* __restrict__ x, const float* __restrict__ dw_b,
    const unsigned int* __restrict__ wpf, unsigned short* __restrict__ yc)
{
  __shared__ unsigned short ring[22*528];

  int bid = blockIdx.x;
  int c = bid % 192;
  int r = bid / 192;
  int xq = r & 1, yq = (r >> 1) & 1, zh = (r >> 2) & 1, b = r >> 3;
  int tx0 = xq*16, ty0 = yq*16, zb = zh*16;

  int tid = threadIdx.x;
  const float* xsrc = x + ((size_t)(b*CCH + c))*NPOS;

  for (int idx = tid; idx < 2904; idx += 256) {
    int sl = idx / 132;
    int rem = idx - sl*132;
    int rr = rem / 6, ci = rem - rr*6;
    int zi = zb - 3 + sl, gy = ty0 - 3 + rr, gx = tx0 - 4 + 4*ci;
    f4v v = {0.f, 0.f, 0.f, 0.f};
    if ((unsigned)zi < 32u && (unsigned)gy < 32u && (unsigned)gx <= 28u)
      v = *(const f4v*)(xsrc + (size_t)zi*1024 + gy*32 + gx);
    union { _Float16 h[4]; uint2 u2; } pk;
    pk.h[0] = (_Float16)v[0]; pk.h[1] = (_Float16)v[1];
    pk.h[2] = (_Float16)v[2]; pk.h[3] = (_Float16)v[3];
    *(uint2*)(ring + sl*528 + rr*24 + ci*4) = pk.u2;
  }
  __syncthreads();

  int p = tid & 15, zl = tid >> 4;
  int px = p & 3, py = p >> 2;
  int y0 = py*4, px4 = px*4;
  const unsigned short* base = ring + zl*528 + y0*24 + px4;
  const unsigned int* wb = wpf + (size_t)c*392;

  float acc[4][4];
  #pragma unroll
  for (int i = 0; i < 4; ++i)
    #pragma unroll
    for (int j = 0; j < 4; ++j) acc[i][j] = 0.f;

  #pragma unroll 1
  for (int s = 0; s < 7; ++s) {
    const unsigned short* sb = base + s*528;
    const unsigned int* wrow = wb + s*56;
    #pragma unroll
    for (int rr = 0; rr < 10; ++rr) {
      const unsigned short* rb = sb + rr*24;
      uint2 q0 = *(const uint2*)(rb);
      uint2 q1 = *(const uint2*)(rb + 4);
      uint2 q2 = *(const uint2*)(rb + 8);
      unsigned int D[6] = {q0.x, q0.y, q1.x, q1.y, q2.x, q2.y};
      #pragma unroll
      for (int dy = 0; dy < 4; ++dy) {
        int ky = rr - dy;
        if (ky < 0 || ky > 6) continue;
        const unsigned int* wk = wrow + ky*8;
        #pragma unroll
        for (int t = 0; t < 4; ++t) {
          DOT2(acc[dy][0], D[t],   wk[t]);
          DOT2(acc[dy][1], D[t+1], wk[4+t]);
          DOT2(acc[dy][2], D[t+1], wk[t]);
          DOT2(acc[dy][3], D[t+2], wk[4+t]);
        }
      }
    }
  }

  float bias = dw_b[c];
  int z = zb + zl;
  int cz = z >> 2, cx = (tx0 >> 2) + px, cy = (ty0 >> 2) + py;
  int cell = cz*64 + cy*8 + cx;
  unsigned short* ybase = yc + (((size_t)(b*512 + cell))*192 + c)*64;
  int tokz = (z & 3)*16;
  #pragma unroll
  for (int dy = 0; dy < 4; ++dy) {
    ushort4 o;
    o.x = f2bf(acc[dy][0] + bias);
    o.y = f2bf(acc[dy][1] + bias);
    o.z = f2bf(acc[dy][2] + bias);
    o.w = f2bf(acc[dy][3] + bias);
    *(ushort4*)(ybase + tokz + dy*4) = o;
  }
}

// ---------------------------------------------------------------------------
// Kernel 1 (tier-3 fallback): fp32 C path.
// ---------------------------------------------------------------------------
__global__ __launch_bounds__(256) void conv_dw_f32_kernel(
    const float* __restrict__ x, const float* __restrict__ dw_w,
    const float* __restrict__ dw_b, unsigned short* __restrict__ yc)
{
  __shared__ float ring[22*528];

  int bid = blockIdx.x;
  int c = bid % 192;
  int r = bid / 192;
  int xq = r & 1, yq = (r >> 1) & 1, zh = (r >> 2) & 1, b = r >> 3;
  int tx0 = xq*16, ty0 = yq*16, zb = zh*16;

  int tid = threadIdx.x;
  const float* xsrc = x + ((size_t)(b*CCH + c))*NPOS;

  for (int idx = tid; idx < 2904; idx += 256) {
    int sl = idx / 132;
    int rem = idx - sl*132;
    int rr = rem / 6, ci = rem - rr*6;
    int zi = zb - 3 + sl, gy = ty0 - 3 + rr, gx = tx0 - 4 + 4*ci;
    f4v v = {0.f, 0.f, 0.f, 0.f};
    if ((unsigned)zi < 32u && (unsigned)gy < 32u && (unsigned)gx <= 28u)
      v = *(const f4v*)(xsrc + (size_t)zi*1024 + gy*32 + gx);
    *(f4v*)(ring + sl*528 + rr*24 + ci*4) = v;
  }
  __syncthreads();

  int p = tid & 15, zl = tid >> 4;
  int px = p & 3, py = p >> 2;
  int y0 = py*4, px4 = px*4;
  const float* base = ring + zl*528 + y0*24 + px4;
  const float* wbase = dw_w + (size_t)c*343;

  f2v acc[8];
  #pragma unroll
  for (int i = 0; i < 8; ++i) acc[i] = (f2v){0.f, 0.f};

  #pragma unroll 1
  for (int s = 0; s < 7; ++s) {
    const float* sb = base + s*528;
    f4v n0 = *(const f4v*)(sb);
    f4v n1 = *(const f4v*)(sb + 4);
    f4v n2 = *(const f4v*)(sb + 8);
    #pragma unroll
    for (int rr = 0; rr < 10; ++rr) {
      f4v r0 = n0, r1 = n1, r2 = n2;
      if (rr < 9) {
        n0 = *(const f4v*)(sb + (rr+1)*24);
        n1 = *(const f4v*)(sb + (rr+1)*24 + 4);
        n2 = *(const f4v*)(sb + (rr+1)*24 + 8);
      }
      f2v pr[10];
      pr[1] = (f2v){r0[1], r0[2]};
      pr[2] = (f2v){r0[2], r0[3]};
      pr[3] = (f2v){r0[3], r1[0]};
      pr[4] = (f2v){r1[0], r1[1]};
      pr[5] = (f2v){r1[1], r1[2]};
      pr[6] = (f2v){r1[2], r1[3]};
      pr[7] = (f2v){r1[3], r2[0]};
      pr[8] = (f2v){r2[0], r2[1]};
      pr[9] = (f2v){r2[1], r2[2]};
      #pragma unroll
      for (int dy = 0; dy < 4; ++dy) {
        int ky = rr - dy;
        if (ky < 0 || ky > 6) continue;
        #pragma unroll
        for (int kx = 0; kx < 7; ++kx) {
          float w = wbase[s*49 + ky*7 + kx];
          f2v wv = (f2v){w, w};
          acc[dy*2+0] = __builtin_elementwise_fma(wv, pr[kx+1], acc[dy*2+0]);
          acc[dy*2+1] = __builtin_elementwise_fma(wv, pr[kx+3], acc[dy*2+1]);
        }
      }
    }
  }

  float bias = dw_b[c];
  int z = zb + zl;
  int cz = z >> 2, cx = (tx0 >> 2) + px, cy = (ty0 >> 2) + py;
  int cell = cz*64 + cy*8 + cx;
  unsigned short* ybase = yc + (((size_t)(b*512 + cell))*192 + c)*64;
  int tokz = (z & 3)*16;
  #pragma unroll
  for (int dy = 0; dy < 4; ++dy) {
    ushort4 o;
    o.x = f2bf(acc[dy*2+0][0] + bias);
    o.y = f2bf(acc[dy*2+0][1] + bias);
    o.z = f2bf(acc[dy*2+1][0] + bias);
    o.w = f2bf(acc[dy*2+1][1] + bias);
    *(ushort4*)(ybase + tokz + dy*4) = o;
  }
}

// ---------------------------------------------------------------------------
// Kernel 2: weight prep (unchanged).
// ---------------------------------------------------------------------------
__global__ __launch_bounds__(256) void prep_w_kernel(
    const float* __restrict__ w1, const float* __restrict__ w2,
    const float* __restrict__ dw_w,
    unsigned short* __restrict__ b1f, unsigned short* __restrict__ b2f,
    unsigned int* __restrict__ wpf, unsigned short* __restrict__ b3f)
{
  int gid = blockIdx.x*256 + threadIdx.x;
  if (gid < 18432) {
    int fi = gid;                         // w1 (C=192 x HID=768)
    int lane = fi & 63, fr = fi >> 6;
    int nt = fr / 6, ks = fr - nt*6;
    int n  = nt*16 + (lane & 15);
    int kb = ks*32 + (lane >> 4)*8;
    #pragma unroll
    for (int j = 0; j < 8; ++j) b1f[fi*8 + j] = f2bf(w1[(kb+j)*HID + n]);
  } else if (gid < 36864) {
    int fi = gid - 18432;                 // w2 (HID=768 x C=192)
    int lane = fi & 63, fr = fi >> 6;
    int nt = fr / 24, ks = fr - nt*24;
    int n  = nt*16 + (lane & 15);
    int kb = ks*32 + (lane >> 4)*8;
    #pragma unroll
    for (int j = 0; j < 8; ++j) b2f[fi*8 + j] = f2bf(w2[(kb+j)*CCH + n]);
  } else if (gid < 46272) {
    int ci = gid - 36864;                 // 192*49 dot2 rows (tier-2)
    int cch = ci / 49, t7 = ci - cch*49;
    const float* wr = dw_w + cch*343 + t7*7;
    float w[8];
    #pragma unroll
    for (int j = 0; j < 7; ++j) w[j] = wr[j];
    w[7] = 0.f;
    union { _Float16 h[2]; unsigned int u; } pk;
    #pragma unroll
    for (int t = 0; t < 4; ++t) {
      pk.h[0] = (t == 0) ? (_Float16)0.f : (_Float16)w[2*t-1];
      pk.h[1] = (_Float16)w[2*t];
      wpf[ci*8 + t] = pk.u;
    }
    #pragma unroll
    for (int t = 0; t < 4; ++t) {
      pk.h[0] = (_Float16)w[2*t];
      pk.h[1] = (_Float16)w[2*t+1];
      wpf[ci*8 + 4 + t] = pk.u;
    }
  } else if (gid < 648384) {
    int fi = gid - 46272;                 // 9408 frags x 64 lanes
    int lane = fi & 63, frag = fi >> 6;
    int cch = frag / 49, tap = frag - cch*49;
    const float* wr = dw_w + cch*343 + tap*7;
    int q = lane >> 4, n = lane & 15;
    h8v pk;
    #pragma unroll
    for (int j = 0; j < 8; ++j) {
      int t = q*8 + j - n - 1;
      pk[j] = (t >= 0 && t <= 6) ? (_Float16)wr[t] : (_Float16)0.f;
    }
    *(h8v*)(b3f + (size_t)fi*8) = pk;
  }
}

// ---------------------------------------------------------------------------
// Kernel 3: fused LN + MLP, 8-WAVE blocks (512 thr), grid 1024. Per-cell
// critical path halved vs r8/r13: GEMM1 N-split (wave w owns h-tile w: 24
// MFMA + 16 gelu), GEMM2 K-split (wave w owns ks2 {(w>>2)*2,+1} x 3 nt: 24
// MFMA). Block still reads b1f/b2f exactly once (waves w,w+4 load disjoint
// ks2). K-partials combined once post-loop via 2-phase LDS reduction
// (24,576 B over dead hbuf/aFrag). 2 active blocks/CU x 8 waves = 16
// waves/CU (was 8). NO min-waves bound (r12 lesson). LDS 40,960 B.
// ---------------------------------------------------------------------------
template<int COMPACT>
__global__ __launch_bounds__(512) void mlp_kernel(
    const unsigned short* __restrict__ yc, const unsigned short* __restrict__ b1f,
    const unsigned short* __restrict__ b2f, const float* __restrict__ b1,
    const float* __restrict__ b2, const float* __restrict__ gamma,
    const float* __restrict__ ln_w, const float* __restrict__ ln_b,
    const int* __restrict__ mask, const int* __restrict__ list,
    float* __restrict__ out)
{
  int bid = blockIdx.x;
  int cid, active;
  if constexpr (COMPACT) {
    int na = list[1024];
    cid = list[bid];
    active = bid < na;
  } else {
    cid = bid;
    active = (mask[bid] != 0);
  }
  int b = cid >> 9, cell = cid & 511;
  int cz = cell >> 6, cy = (cell >> 3) & 7, cx = cell & 7;
  int z0 = cz*4, y0 = cy*4, x0 = cx*4;
  int tid = threadIdx.x, wave = tid >> 6, lane = tid & 63;
  int lq = lane >> 4, ln15 = lane & 15;

  if (!active) {
    f4v z4 = {0.f, 0.f, 0.f, 0.f};
    #pragma unroll
    for (int pp = 0; pp < 6; ++pp) {
      int i4 = tid + 512*pp;              // 0..3071
      int c = i4 >> 4, rem = i4 & 15;
      int dz = rem >> 2, dy = rem & 3;
      *(f4v*)(out + ((size_t)(b*CCH + c))*NPOS
                  + (size_t)(z0+dz)*1024 + (y0+dy)*32 + x0) = z4;
    }
    return;
  }

  // ---- LDS: hbuf (ch loop) over sred/murs (pre) over redu (post); aFrag
  __shared__ __align__(16) char lds[40960];
  unsigned short* hbuf = (unsigned short*)lds;            // 8192 ushorts
  float* sred = (float*)lds;                              // 16*64 floats
  float* murs = (float*)(lds + 4096);                     // 2*64 floats
  float* redu = (float*)lds;                              // 24,576 B (post-loop)
  unsigned short* aFrag = (unsigned short*)(lds + 16384); // 12288 ushorts

  const unsigned short* ysrc = yc + (size_t)cid*12288;

  // ---- LN stats straight from global: part = tid>>6 (8 parts x 24 ch)
  {
    int tok = tid & 63, part = tid >> 6;
    float S = 0.f, Q = 0.f;
    #pragma unroll
    for (int j = 0; j < 24; ++j) {
      float v = bf2f(ysrc[(part*24 + j)*64 + tok]);
      S += v; Q = fmaf(v, v, Q);
    }
    sred[part*64 + tok] = S; sred[(8 + part)*64 + tok] = Q;
  }
  __syncthreads();
  if (tid < 64) {
    float S = 0.f, Q = 0.f;
    #pragma unroll
    for (int p = 0; p < 8; ++p) { S += sred[p*64 + tid]; Q += sred[(8+p)*64 + tid]; }
    float m = S*(1.f/192.f);
    float var = Q*(1.f/192.f) - m*m;
    murs[tid] = m;
    murs[64 + tid] = rsqrtf(var + 1e-6f);
  }
  __syncthreads();

  // ---- build A-fragments from global yc (3 frags/thread)
  #pragma unroll
  for (int k = 0; k < 3; ++k) {
    int fi = tid + 512*k;                   // 0..1535
    int lane2 = fi & 63, rest = fi >> 6;
    int mt = rest / 6, ks = rest - mt*6;
    int tok = mt*16 + (lane2 & 15);
    int cc0 = ks*32 + (lane2 >> 4)*8;
    float m = murs[tok], rs = murs[64 + tok];
    f4v lw0 = *(const f4v*)(ln_w + cc0), lw1 = *(const f4v*)(ln_w + cc0 + 4);
    f4v lb0 = *(const f4v*)(ln_b + cc0), lb1 = *(const f4v*)(ln_b + cc0 + 4);
    union { bf8v v; unsigned short u[8]; } pk;
    #pragma unroll
    for (int j = 0; j < 4; ++j) {
      float v0 = (bf2f(ysrc[(cc0+j)*64 + tok])   - m)*rs*lw0[j] + lb0[j];
      float v1 = (bf2f(ysrc[(cc0+4+j)*64 + tok]) - m)*rs*lw1[j] + lb1[j];
      pk.u[j] = f2bf(v0); pk.u[4+j] = f2bf(v1);
    }
    *(bf8v*)(aFrag + fi*8) = pk.v;
  }
  __syncthreads();                          // murs dead; hbuf writable after

  f4v acc2[4][3];
  #pragma unroll
  for (int mt = 0; mt < 4; ++mt)
    #pragma unroll
    for (int nt = 0; nt < 3; ++nt)
      acc2[mt][nt] = (f4v){0.f, 0.f, 0.f, 0.f};

  int ks2b = (wave >> 2)*2;                // GEMM2 K-half
  int w3 = (wave & 3)*3;                   // GEMM2 nt group
  int khalf = wave >> 1;                   // hbuf ks2 slice written by this wave
  int lane_hi = (wave & 1)*2 + (ln15 >> 3);

  const unsigned short* p1base = b1f + wave*6*512 + lane*8;        // + ch*24576
  const unsigned short* p2base = b2f + (size_t)w3*12288 + lane*8;  // + nt*12288 + (ch*4+ks2)*512

  bf8v B1r[6];
  #pragma unroll
  for (int ks = 0; ks < 6; ++ks)            // preload B1 for ch=0
    B1r[ks] = *(const bf8v*)(p1base + ks*512);

  #pragma unroll 1
  for (int ch = 0; ch < 6; ++ch) {
    // ---- B2r(ch): this wave's K-half x 3 nt; drain covered by GEMM1
    bf8v B2r[6];
    const unsigned short* p2 = p2base + ch*2048;
    #pragma unroll
    for (int k2 = 0; k2 < 2; ++k2)
      #pragma unroll
      for (int nt = 0; nt < 3; ++nt)
        B2r[k2*3 + nt] = *(const bf8v*)(p2 + nt*12288 + (ks2b + k2)*512);

    // ---- GEMM1: wave w owns h-tile w (N-split), 24 MFMAs
    f4v a1[4];
    #pragma unroll
    for (int mt = 0; mt < 4; ++mt) a1[mt] = (f4v){0.f,0.f,0.f,0.f};
    #pragma unroll
    for (int ks = 0; ks < 6; ++ks) {
      #pragma unroll
      for (int mt = 0; mt < 4; ++mt) {
        bf8v Af = *(const bf8v*)(aFrag + ((mt*6 + ks)*64 + lane)*8);
        a1[mt] = __builtin_amdgcn_mfma_f32_16x16x32_bf16(Af, B1r[ks], a1[mt], 0, 0, 0);
      }
    }

    // ---- prefetch B1r(ch+1): drain covered by gelu + barrier + GEMM2
    if (ch < 5) {
      const unsigned short* p1 = p1base + (ch+1)*24576;
      #pragma unroll
      for (int ks = 0; ks < 6; ++ks)
        B1r[ks] = *(const bf8v*)(p1 + ks*512);
    }

    // ---- bias + gelu -> hbuf (A2-frag order); wave w writes ks2=w>>1 half
    {
      float b1v = b1[(ch*8 + wave)*16 + ln15];
      #pragma unroll
      for (int mt = 0; mt < 4; ++mt)
        #pragma unroll
        for (int rr = 0; rr < 4; ++rr) {
          float g = gelu_f(a1[mt][rr] + b1v);
          int elem = ((mt*4 + khalf)*64 + lane_hi*16 + (lq*4 + rr))*8 + (lane & 7);
          hbuf[elem] = f2bf(g);
        }
    }
    __syncthreads();
    // ---- GEMM2 partial: wave w does its K-half x 3 nt, 24 MFMAs
    #pragma unroll
    for (int k2 = 0; k2 < 2; ++k2) {
      int ks2 = ks2b + k2;
      bf8v A2[4];
      #pragma unroll
      for (int mt = 0; mt < 4; ++mt)
        A2[mt] = *(const bf8v*)(hbuf + ((mt*4 + ks2)*64 + lane)*8);
      #pragma unroll
      for (int nt = 0; nt < 3; ++nt)
        #pragma unroll
        for (int mt = 0; mt < 4; ++mt)
          acc2[mt][nt] = __builtin_amdgcn_mfma_f32_16x16x32_bf16(A2[mt], B2r[k2*3+nt], acc2[mt][nt], 0, 0, 0);
    }
    __syncthreads();                        // hbuf reused next ch
  }

  // ---- K-reduction: waves 4..7 partials folded into waves 0..3 (2 phases)
  #pragma unroll
  for (int half = 0; half < 2; ++half) {
    if (wave >= 4) {
      int base = ((wave - 4)*64 + lane)*24;
      #pragma unroll
      for (int m2 = 0; m2 < 2; ++m2)
        #pragma unroll
        for (int nt = 0; nt < 3; ++nt)
          *(f4v*)(redu + base + (m2*3 + nt)*4) = acc2[half*2 + m2][nt];
    }
    __syncthreads();
    if (wave < 4) {
      int base = (wave*64 + lane)*24;
      #pragma unroll
      for (int m2 = 0; m2 < 2; ++m2)
        #pragma unroll
        for (int nt = 0; nt < 3; ++nt) {
          f4v p = *(const f4v*)(redu + base + (m2*3 + nt)*4);
          acc2[half*2 + m2][nt] += p;
        }
    }
    __syncthreads();
  }

  // ---- epilogue (waves 0..3): gamma*(acc+b2), f4v store channels-first
  if (wave < 4) {
    #pragma unroll
    for (int nt = 0; nt < 3; ++nt) {
      int c = (w3 + nt)*16 + ln15;
      float gm = gamma[c], bb = b2[c];
      size_t cbase = ((size_t)(b*CCH + c))*NPOS + (size_t)(y0 + lq)*32 + x0;
      #pragma unroll
      for (int mt = 0; mt < 4; ++mt) {
        f4v o;
        o[0] = gm*(acc2[mt][nt][0] + bb);
        o[1] = gm*(acc2[mt][nt][1] + bb);
        o[2] = gm*(acc2[mt][nt][2] + bb);
        o[3] = gm*(acc2[mt][nt][3] + bb);
        *(f4v*)(out + cbase + (size_t)(z0 + mt)*1024) = o;
      }
    }
  }
}

// ---------------------------------------------------------------------------
extern "C" void kernel_launch(void* const* d_in, const int* in_sizes, int n_in,
                              void* d_out, int out_size, void* d_ws, size_t ws_size,
                              hipStream_t stream) {
  const float* x     = (const float*)d_in[0];
  const int*   mask  = (const int*)  d_in[1];
  const float* dw_w  = (const float*)d_in[2];
  const float* dw_b  = (const float*)d_in[3];
  const float* ln_w  = (const float*)d_in[4];
  const float* ln_b  = (const float*)d_in[5];
  const float* w1    = (const float*)d_in[6];
  const float* b1    = (const float*)d_in[7];
  const float* w2    = (const float*)d_in[8];
  const float* b2    = (const float*)d_in[9];
  const float* gamma = (const float*)d_in[10];
  float* out = (float*)d_out;
  char* ws = (char*)d_ws;

  unsigned short* yc  = (unsigned short*)(ws + WS_Y);
  unsigned short* b1f = (unsigned short*)(ws + WS_B1F);
  unsigned short* b2f = (unsigned short*)(ws + WS_B2F);
  unsigned int*   wpf = (unsigned int*)(ws + WS_WPF);
  unsigned short* b3f = (unsigned short*)(ws + WS_B3F);
  int*            lst = (int*)(ws + WS_WPF);   // mfma tier: wpf slot unused

  bool mfma_ok = ws_size >= WS_TOTAL_MFMA;
  bool dot2_ok = ws_size >= WS_TOTAL_DOT2;
  int prep_grid = mfma_ok ? 2533 : (dot2_ok ? 181 : 144);
  prep_w_kernel<<<prep_grid, 256, 0, stream>>>(w1, w2, dw_w, b1f, b2f, wpf, b3f);
  if (mfma_ok) {
    compact_kernel<<<1, 256, 0, stream>>>(mask, lst);
    conv_mfma_kernel<<<3072, 256, 0, stream>>>(x, dw_b, b3f, yc);
    mlp_kernel<1><<<1024, 512, 0, stream>>>(yc, b1f, b2f, b1, b2, gamma, ln_w, ln_b, mask, lst, out);
  } else if (dot2_ok) {
    conv_dw_f16_kernel<<<3072, 256, 0, stream>>>(x, dw_b, wpf, yc);
    mlp_kernel<0><<<1024, 512, 0, stream>>>(yc, b1f, b2f, b1, b2, gamma, ln_w, ln_b, mask, nullptr, out);
  } else {
    conv_dw_f32_kernel<<<3072, 256, 0, stream>>>(x, dw_w, dw_b, yc);
    mlp_kernel<0><<<1024, 512, 0, stream>>>(yc, b1f, b2f, b1, b2, gamma, ln_w, ln_b, mask, nullptr, out);
  }
}